// Round 1
// baseline (19844.887 us; speedup 1.0000x reference)
//
#include <hip/hip_runtime.h>
#include <hip/hip_fp16.h>

// Problem constants
#define BB 1024   // batch
#define TT 512    // timesteps
#define EE 100    // embedding dim
#define H1C 128   // hidden 1
#define G1C 512   // 4*H1
#define H2C 64    // hidden 2
#define G2C 256   // 4*H2
#define NB 4      // batch elements per block

// readlane: broadcast lane's value to an SGPR (wave-uniform). lane must be uniform.
__device__ __forceinline__ float rl(float v, int lane) {
    return __builtin_bit_cast(float, __builtin_amdgcn_readlane(__builtin_bit_cast(int, v), lane));
}
__device__ __forceinline__ float2 upk(unsigned int p) {
    __half2 h = __builtin_bit_cast(__half2, p);
    return __half22float2(h);
}
__device__ __forceinline__ unsigned int pk(float a, float b) {
    __half2 h;
    h.x = __float2half(a);
    h.y = __float2half(b);
    return __builtin_bit_cast(unsigned int, h);
}
__device__ __forceinline__ float sigm(float x) {
    return 1.0f / (1.0f + __expf(-x));
}
__device__ __forceinline__ float tanh_(float x) {
    float t = __expf(-2.0f * fabsf(x));
    float r = (1.0f - t) / (1.0f + t);
    return copysignf(r, x);
}

// Fused 2-layer LSTM scan + FC head. One block = NB batch elements, all T steps.
// Thread t owns L1 gate row t (fp16-packed W1_ih row: 50 regs, W1_hh row: 64 regs)
// and half of L2 gate row (t&255): W2_ih half-row 32 regs, W2_hh half-row 16 regs.
extern "C" __global__ void __launch_bounds__(512, 2)
lstm_fused(const float* __restrict__ X,
           const float* __restrict__ W1ih, const float* __restrict__ W1hh,
           const float* __restrict__ b1i,  const float* __restrict__ b1h,
           const float* __restrict__ W2ih, const float* __restrict__ W2hh,
           const float* __restrict__ b2i,  const float* __restrict__ b2h,
           const float* __restrict__ fc1w, const float* __restrict__ fc1b,
           const float* __restrict__ fc2w, const float* __restrict__ fc2b,
           float* __restrict__ out)
{
    const int tid  = threadIdx.x;
    const int lane = tid & 63;
    const int b0   = blockIdx.x * NB;
    const int hf   = tid >> 8;    // 0/1: which K-half of the L2 row this thread does
    const int t2   = tid & 255;   // L2 gate row
    const int gsel = tid >> 7;    // 0:i 1:f 2:g 3:o for layer 1

    __shared__ float act1[NB][G1C];      // activated L1 gates        (8 KB)
    __shared__ float h1s[NB][H1C];       // h1 broadcast buffer       (2 KB)
    __shared__ float part2[2][NB][G2C];  // L2 gate partial sums      (8 KB)
    __shared__ float h2s[NB][H2C];       // h2 broadcast buffer       (1 KB)
    __shared__ float fcb[NB][32];        // fc1 activations           (0.5 KB)

    // ---- load weights into registers (fp16-packed pairs), one-time ----
    unsigned int wih[50], whh[64], w2i[32], w2h[16];
#pragma unroll
    for (int i = 0; i < 50; ++i) wih[i] = pk(W1ih[tid * EE + 2 * i], W1ih[tid * EE + 2 * i + 1]);
#pragma unroll
    for (int i = 0; i < 64; ++i) whh[i] = pk(W1hh[tid * H1C + 2 * i], W1hh[tid * H1C + 2 * i + 1]);
    {
        const int bi = t2 * H1C + hf * 64;
#pragma unroll
        for (int i = 0; i < 32; ++i) w2i[i] = pk(W2ih[bi + 2 * i], W2ih[bi + 2 * i + 1]);
        const int bh = t2 * H2C + hf * 32;
#pragma unroll
        for (int i = 0; i < 16; ++i) w2h[i] = pk(W2hh[bh + 2 * i], W2hh[bh + 2 * i + 1]);
    }
    const float bias1 = b1i[tid] + b1h[tid];
    const float bias2 = (hf == 0) ? (b2i[t2] + b2h[t2]) : 0.0f;

    // ---- recurrent state ----
    float hv0[NB], hv1[NB], h2v[NB], c1[NB], c2[NB];
    float xc0[NB], xc1[NB], xn0[NB], xn1[NB];
#pragma unroll
    for (int nb = 0; nb < NB; ++nb) { hv0[nb] = hv1[nb] = h2v[nb] = c1[nb] = c2[nb] = 0.0f; }

    // preload x(t=0): lane l holds x[nb][l] and x[nb][64+l]
#pragma unroll
    for (int nb = 0; nb < NB; ++nb) {
        const float* xr = X + ((b0 + nb) * TT + 0) * EE;
        xc0[nb] = xr[lane];
        xc1[nb] = (lane < EE - 64) ? xr[64 + lane] : 0.0f;
    }

    for (int t = 0; t < TT; ++t) {
        // ---- phase 1: L1 gates. acc[nb] = b + W1ih[row]*x[nb] + W1hh[row]*h1[nb]
        float acc[NB];
#pragma unroll
        for (int nb = 0; nb < NB; ++nb) acc[nb] = bias1;
#pragma unroll
        for (int i = 0; i < 50; ++i) {
            float2 w = upk(wih[i]);
#pragma unroll
            for (int nb = 0; nb < NB; ++nb) {
                float x0 = rl((2 * i < 64) ? xc0[nb] : xc1[nb], (2 * i) & 63);
                float x1 = rl((2 * i + 1 < 64) ? xc0[nb] : xc1[nb], (2 * i + 1) & 63);
                acc[nb] += w.x * x0 + w.y * x1;
            }
        }
        // prefetch next step's x while doing hh + epilogue phases
        {
            const int tn = (t + 1 < TT) ? (t + 1) : t;
#pragma unroll
            for (int nb = 0; nb < NB; ++nb) {
                const float* xr = X + ((b0 + nb) * TT + tn) * EE;
                xn0[nb] = xr[lane];
                xn1[nb] = (lane < EE - 64) ? xr[64 + lane] : 0.0f;
            }
        }
#pragma unroll
        for (int i = 0; i < 64; ++i) {
            float2 w = upk(whh[i]);
#pragma unroll
            for (int nb = 0; nb < NB; ++nb) {
                float h0 = rl((2 * i < 64) ? hv0[nb] : hv1[nb], (2 * i) & 63);
                float h1 = rl((2 * i + 1 < 64) ? hv0[nb] : hv1[nb], (2 * i + 1) & 63);
                acc[nb] += w.x * h0 + w.y * h1;
            }
        }
        // activation (wave-uniform branch: gsel constant per wave)
#pragma unroll
        for (int nb = 0; nb < NB; ++nb) {
            float a = acc[nb];
            act1[nb][tid] = (gsel == 2) ? tanh_(a) : sigm(a);
        }
        __syncthreads();

        // ---- phase 2: h1/c1 update (threads 0..127, j = tid)
        if (tid < H1C) {
#pragma unroll
            for (int nb = 0; nb < NB; ++nb) {
                float i_ = act1[nb][tid];
                float f_ = act1[nb][H1C + tid];
                float g_ = act1[nb][2 * H1C + tid];
                float o_ = act1[nb][3 * H1C + tid];
                float c  = f_ * c1[nb] + i_ * g_;
                c1[nb]   = c;
                h1s[nb][tid] = o_ * tanh_(c);
            }
        }
        __syncthreads();

        // ---- phase 3: redistribute h1, compute L2 gate partials
#pragma unroll
        for (int nb = 0; nb < NB; ++nb) {
            hv0[nb] = h1s[nb][lane];
            hv1[nb] = h1s[nb][64 + lane];
        }
        float acc2[NB];
#pragma unroll
        for (int nb = 0; nb < NB; ++nb) acc2[nb] = bias2;
        float hsrc[NB];
#pragma unroll
        for (int nb = 0; nb < NB; ++nb) hsrc[nb] = hf ? hv1[nb] : hv0[nb];
#pragma unroll
        for (int i = 0; i < 32; ++i) {   // W2_ih half-row · h1 half
            float2 w = upk(w2i[i]);
#pragma unroll
            for (int nb = 0; nb < NB; ++nb) {
                float x0 = rl(hsrc[nb], 2 * i);
                float x1 = rl(hsrc[nb], 2 * i + 1);
                acc2[nb] += w.x * x0 + w.y * x1;
            }
        }
        const int klo = hf * 32;
#pragma unroll
        for (int i = 0; i < 16; ++i) {   // W2_hh half-row · h2 half
            float2 w = upk(w2h[i]);
#pragma unroll
            for (int nb = 0; nb < NB; ++nb) {
                float x0 = rl(h2v[nb], klo + 2 * i);
                float x1 = rl(h2v[nb], klo + 2 * i + 1);
                acc2[nb] += w.x * x0 + w.y * x1;
            }
        }
#pragma unroll
        for (int nb = 0; nb < NB; ++nb) part2[hf][nb][t2] = acc2[nb];
        __syncthreads();

        // ---- phase 4: h2/c2 update (threads 0..63, j = tid)
        if (tid < H2C) {
#pragma unroll
            for (int nb = 0; nb < NB; ++nb) {
                float i_ = sigm(part2[0][nb][tid]           + part2[1][nb][tid]);
                float f_ = sigm(part2[0][nb][H2C + tid]     + part2[1][nb][H2C + tid]);
                float g_ = tanh_(part2[0][nb][2 * H2C + tid] + part2[1][nb][2 * H2C + tid]);
                float o_ = sigm(part2[0][nb][3 * H2C + tid] + part2[1][nb][3 * H2C + tid]);
                float c  = f_ * c2[nb] + i_ * g_;
                c2[nb]   = c;
                h2s[nb][tid] = o_ * tanh_(c);
            }
        }
        __syncthreads();
#pragma unroll
        for (int nb = 0; nb < NB; ++nb) h2v[nb] = h2s[nb][lane];
        // rotate prefetched x
#pragma unroll
        for (int nb = 0; nb < NB; ++nb) { xc0[nb] = xn0[nb]; xc1[nb] = xn1[nb]; }
    }

    // ---- FC head: relu(h2 @ fc1^T + b) @ fc2^T + b -> sigmoid
    if (tid < NB * 32) {
        int nb = tid >> 5, o = tid & 31;
        float s = fc1b[o];
#pragma unroll
        for (int k = 0; k < H2C; ++k) s += fc1w[o * H2C + k] * h2s[nb][k];
        fcb[nb][o] = fmaxf(s, 0.0f);
    }
    __syncthreads();
    if (tid < NB) {
        float s = fc2b[0];
#pragma unroll
        for (int k = 0; k < 32; ++k) s += fc2w[k] * fcb[tid][k];
        out[b0 + tid] = sigm(s);
    }
}

extern "C" void kernel_launch(void* const* d_in, const int* in_sizes, int n_in,
                              void* d_out, int out_size, void* d_ws, size_t ws_size,
                              hipStream_t stream) {
    const float* X    = (const float*)d_in[0];
    const float* W1ih = (const float*)d_in[1];
    const float* W1hh = (const float*)d_in[2];
    const float* b1i  = (const float*)d_in[3];
    const float* b1h  = (const float*)d_in[4];
    const float* W2ih = (const float*)d_in[5];
    const float* W2hh = (const float*)d_in[6];
    const float* b2i  = (const float*)d_in[7];
    const float* b2h  = (const float*)d_in[8];
    const float* fc1w = (const float*)d_in[9];
    const float* fc1b = (const float*)d_in[10];
    const float* fc2w = (const float*)d_in[11];
    const float* fc2b = (const float*)d_in[12];

    hipLaunchKernelGGL(lstm_fused, dim3(BB / NB), dim3(512), 0, stream,
                       X, W1ih, W1hh, b1i, b1h, W2ih, W2hh, b2i, b2h,
                       fc1w, fc1b, fc2w, fc2b, (float*)d_out);
}

// Round 2
// 1296.281 us; speedup vs baseline: 15.3091x; 15.3091x over previous
//
#include <hip/hip_runtime.h>
#include <hip/hip_fp16.h>

typedef _Float16 half8 __attribute__((ext_vector_type(8)));
typedef _Float16 half4 __attribute__((ext_vector_type(4)));
typedef float floatx4 __attribute__((ext_vector_type(4)));

#define BB 1024
#define TT 512
#define EE 100
#define NBATCH 16   // batches per block
#define XSTR 136    // padded row stride (halfs) for x and h1 (128 data + pad)
#define H2STR 72    // padded row stride (halfs) for h2 / gate-exchange

__device__ __forceinline__ float sigm(float x) {
    return __builtin_amdgcn_rcpf(1.0f + __expf(-x));
}
__device__ __forceinline__ float tanh_(float x) {
    float t = __expf(-2.0f * fabsf(x));
    float r = (1.0f - t) * __builtin_amdgcn_rcpf(1.0f + t);
    return copysignf(r, x);
}

// One block = 16 batch elements, all 512 timesteps, both LSTM layers + FC head.
// 8 waves. Wave w owns L1 unit slice [16w,16w+16) across all four gates
// (tiles {w, w+8, w+16, w+24}), so i/f/g/o accumulators align per-lane and the
// cell update never leaves registers. L2: waves 0-3 own gates i,f and waves
// 4-7 own g,o for unit slice [16(w&3), +16); g/o activations cross via LDS.
extern "C" __global__ void __launch_bounds__(512, 2)
lstm_mfma(const float* __restrict__ X,
          const float* __restrict__ W1ih, const float* __restrict__ W1hh,
          const float* __restrict__ b1i,  const float* __restrict__ b1h,
          const float* __restrict__ W2ih, const float* __restrict__ W2hh,
          const float* __restrict__ b2i,  const float* __restrict__ b2h,
          const float* __restrict__ fc1w, const float* __restrict__ fc1b,
          const float* __restrict__ fc2w, const float* __restrict__ fc2b,
          float* __restrict__ out)
{
    const int tid  = threadIdx.x;
    const int w    = tid >> 6;     // wave 0..7
    const int lane = tid & 63;
    const int q    = lane >> 4;    // quad 0..3
    const int m    = lane & 15;    // A-row / B-col / C-col index
    const int b0   = blockIdx.x * NBATCH;
    const int p2   = w & 3;        // L2 unit-slice group
    const int gh   = w >> 2;       // 0: gates i,f   1: gates g,o

    __shared__ __align__(16) _Float16 xb [2][NBATCH][XSTR];
    __shared__ __align__(16) _Float16 h1b[2][NBATCH][XSTR];
    __shared__ __align__(16) _Float16 h2b[2][NBATCH][H2STR];
    __shared__ __align__(16) _Float16 gob[2][NBATCH][H2STR];
    __shared__ float fca[NBATCH][32];

    // ---- zero-init LDS state ----
    {
        _Float16* px  = &xb[0][0][0];
        _Float16* ph1 = &h1b[0][0][0];
        for (int i = tid; i < 2 * NBATCH * XSTR; i += 512) { px[i] = (_Float16)0.0f; ph1[i] = (_Float16)0.0f; }
        _Float16* ph2 = &h2b[0][0][0];
        for (int i = tid; i < 2 * NBATCH * H2STR; i += 512) ph2[i] = (_Float16)0.0f;
    }

    // ---- weight fragments (fp16) in registers ----
    half8 w1ihf[4][4], w1hhf[4][4], w2ihf[2][4], w2hhf[2][2];
    floatx4 bias2v[2];
#pragma unroll
    for (int g = 0; g < 4; ++g) {
        const int r = g * 128 + 16 * w + m;
        const float bias = b1i[r] + b1h[r];
#pragma unroll
        for (int s = 0; s < 4; ++s) {
            half8 f;
#pragma unroll
            for (int j = 0; j < 8; ++j) {
                const int k = 32 * s + 8 * q + j;
                float v = 0.0f;
                if (k < EE) v = W1ih[r * EE + k];
                else if (k == EE) v = bias;      // bias column: pairs with xb[..][100]=1
                f[j] = (_Float16)v;
            }
            w1ihf[g][s] = f;
        }
#pragma unroll
        for (int s = 0; s < 4; ++s) {
            half8 f;
#pragma unroll
            for (int j = 0; j < 8; ++j) f[j] = (_Float16)W1hh[r * 128 + 32 * s + 8 * q + j];
            w1hhf[g][s] = f;
        }
    }
#pragma unroll
    for (int tau = 0; tau < 2; ++tau) {
        const int g = gh * 2 + tau;
        const int r = g * 64 + 16 * p2 + m;
#pragma unroll
        for (int s = 0; s < 4; ++s) {
            half8 f;
#pragma unroll
            for (int j = 0; j < 8; ++j) f[j] = (_Float16)W2ih[r * 128 + 32 * s + 8 * q + j];
            w2ihf[tau][s] = f;
        }
#pragma unroll
        for (int s = 0; s < 2; ++s) {
            half8 f;
#pragma unroll
            for (int j = 0; j < 8; ++j) f[j] = (_Float16)W2hh[r * 64 + 32 * s + 8 * q + j];
            w2hhf[tau][s] = f;
        }
#pragma unroll
        for (int reg = 0; reg < 4; ++reg) {   // bias in C-layout rows (4q+reg)
            const int rr = g * 64 + 16 * p2 + 4 * q + reg;
            bias2v[tau][reg] = b2i[rr] + b2h[rr];
        }
    }

    // ---- x staging thread->element map (invariant over t) ----
    int xgbase[4], xloff[4];
    const bool v3 = (tid < 64);   // only first 64 threads have a 4th element
#pragma unroll
    for (int j = 0; j < 4; ++j) {
        const int i = tid + 512 * j;        // 0..2047, valid < 1600
        const int n = i / 100;
        const int e = i - n * 100;
        const int nn = (n < NBATCH) ? n : 0;  // clamp to keep addresses sane
        xgbase[j] = ((b0 + nn) * TT) * EE + e;
        xloff[j]  = nn * XSTR + e;
    }

    __syncthreads();
    // bias-one columns + stage x(0)
    if (tid < 32) { const int s = tid >> 4, n = tid & 15; xb[s][n][EE] = (_Float16)1.0f; }
#pragma unroll
    for (int j = 0; j < 4; ++j)
        if (j < 3 || v3) xb[0][0][xloff[j]] = (_Float16)X[xgbase[j]];
    __syncthreads();

    floatx4 c1 = {0.f, 0.f, 0.f, 0.f};
    floatx4 c2 = {0.f, 0.f, 0.f, 0.f};

#pragma unroll 1
    for (int t = 0; t < TT; ++t) {
        const int cur = t & 1, oth = cur ^ 1;

        // ---- phase A: L1 gates  (A=W1 fragments, B=x/h1 from LDS) ----
        floatx4 a1[4];
#pragma unroll
        for (int g = 0; g < 4; ++g) a1[g] = (floatx4){0.f, 0.f, 0.f, 0.f};
#pragma unroll
        for (int s = 0; s < 4; ++s) {
            half8 bx = *(const half8*)&xb[cur][m][32 * s + 8 * q];
#pragma unroll
            for (int g = 0; g < 4; ++g)
                a1[g] = __builtin_amdgcn_mfma_f32_16x16x32_f16(w1ihf[g][s], bx, a1[g], 0, 0, 0);
        }
#pragma unroll
        for (int s = 0; s < 4; ++s) {
            half8 bh = *(const half8*)&h1b[oth][m][32 * s + 8 * q];
#pragma unroll
            for (int g = 0; g < 4; ++g)
                a1[g] = __builtin_amdgcn_mfma_f32_16x16x32_f16(w1hhf[g][s], bh, a1[g], 0, 0, 0);
        }

        // issue next-step x loads early (latency hiding across phase B)
        const int nst = (t + 1 < TT) ? (t + 1) : (TT - 1);
        float xs[4];
#pragma unroll
        for (int j = 0; j < 4; ++j)
            if (j < 3 || v3) xs[j] = X[xgbase[j] + nst * EE];

        // ---- epilogue 1: cell update fully in registers ----
        {
            half4 hv;
#pragma unroll
            for (int r = 0; r < 4; ++r) {
                const float i_ = sigm(a1[0][r]);
                const float f_ = sigm(a1[1][r]);
                const float g_ = tanh_(a1[2][r]);
                const float o_ = sigm(a1[3][r]);
                const float c  = f_ * c1[r] + i_ * g_;
                c1[r] = c;
                hv[r] = (_Float16)(o_ * tanh_(c));
            }
            *(half4*)&h1b[cur][m][16 * w + 4 * q] = hv;
        }
        __syncthreads();   // h1(t) visible

        // ---- phase B: L2 gates ----
        floatx4 a2[2] = { bias2v[0], bias2v[1] };
#pragma unroll
        for (int s = 0; s < 4; ++s) {
            half8 bh = *(const half8*)&h1b[cur][m][32 * s + 8 * q];
            a2[0] = __builtin_amdgcn_mfma_f32_16x16x32_f16(w2ihf[0][s], bh, a2[0], 0, 0, 0);
            a2[1] = __builtin_amdgcn_mfma_f32_16x16x32_f16(w2ihf[1][s], bh, a2[1], 0, 0, 0);
        }
#pragma unroll
        for (int s = 0; s < 2; ++s) {
            half8 b2 = *(const half8*)&h2b[oth][m][32 * s + 8 * q];
            a2[0] = __builtin_amdgcn_mfma_f32_16x16x32_f16(w2hhf[0][s], b2, a2[0], 0, 0, 0);
            a2[1] = __builtin_amdgcn_mfma_f32_16x16x32_f16(w2hhf[1][s], b2, a2[1], 0, 0, 0);
        }

        // write staged x(t+1)
        {
            _Float16* xd = &xb[oth][0][0];
#pragma unroll
            for (int j = 0; j < 4; ++j)
                if (j < 3 || v3) xd[xloff[j]] = (_Float16)xs[j];
        }

        if (w >= 4) {   // gates g,o: activate and hand to waves 0-3
            half4 tg, so;
#pragma unroll
            for (int r = 0; r < 4; ++r) {
                tg[r] = (_Float16)tanh_(a2[0][r]);
                so[r] = (_Float16)sigm(a2[1][r]);
            }
            *(half4*)&gob[0][m][16 * p2 + 4 * q] = tg;
            *(half4*)&gob[1][m][16 * p2 + 4 * q] = so;
        }
        __syncthreads();   // g,o visible; x(t+1) visible

        if (w < 4) {       // epilogue 2: c2/h2 update
            half4 tg = *(const half4*)&gob[0][m][16 * p2 + 4 * q];
            half4 so = *(const half4*)&gob[1][m][16 * p2 + 4 * q];
            half4 h2v;
#pragma unroll
            for (int r = 0; r < 4; ++r) {
                const float c = sigm(a2[1][r]) * c2[r] + sigm(a2[0][r]) * (float)tg[r];
                c2[r] = c;
                h2v[r] = (_Float16)((float)so[r] * tanh_(c));
            }
            *(half4*)&h2b[cur][m][16 * p2 + 4 * q] = h2v;
        }
        // next iteration's barrier(1) orders h2(t) before its phase-B readers
    }
    __syncthreads();

    // ---- FC head ----
    {
        const int fs = (TT - 1) & 1;
        const int nb = tid >> 5, o = tid & 31;
        float s = fc1b[o];
#pragma unroll
        for (int k = 0; k < 64; ++k) s += fc1w[o * 64 + k] * (float)h2b[fs][nb][k];
        fca[nb][o] = fmaxf(s, 0.0f);
    }
    __syncthreads();
    if (tid < NBATCH) {
        float s = fc2b[0];
#pragma unroll
        for (int k = 0; k < 32; ++k) s += fc2w[k] * fca[tid][k];
        out[b0 + tid] = sigm(s);
    }
}

extern "C" void kernel_launch(void* const* d_in, const int* in_sizes, int n_in,
                              void* d_out, int out_size, void* d_ws, size_t ws_size,
                              hipStream_t stream) {
    const float* X    = (const float*)d_in[0];
    const float* W1ih = (const float*)d_in[1];
    const float* W1hh = (const float*)d_in[2];
    const float* b1i  = (const float*)d_in[3];
    const float* b1h  = (const float*)d_in[4];
    const float* W2ih = (const float*)d_in[5];
    const float* W2hh = (const float*)d_in[6];
    const float* b2i  = (const float*)d_in[7];
    const float* b2h  = (const float*)d_in[8];
    const float* fc1w = (const float*)d_in[9];
    const float* fc1b = (const float*)d_in[10];
    const float* fc2w = (const float*)d_in[11];
    const float* fc2b = (const float*)d_in[12];

    hipLaunchKernelGGL(lstm_mfma, dim3(BB / NBATCH), dim3(512), 0, stream,
                       X, W1ih, W1hh, b1i, b1h, W2ih, W2hh, b2i, b2h,
                       fc1w, fc1b, fc2w, fc2b, (float*)d_out);
}